// Round 19
// baseline (314.834 us; speedup 1.0000x reference)
//
#include <hip/hip_runtime.h>
#include <hip/hip_bf16.h>
#include <stdint.h>

// Problem shape (fixed by setup_inputs)
#define Hh 12
#define Dm 768
#define Bb 16
#define Nt 1569       // 1 + 8*196 tokens
#define Ff 8
#define NC 196        // chunk length
#define BH 192        // B*H
#define Mr 25104      // B*Nt rows
#define CPW 224       // per-chunk padded width in vT (multiple of 32)
#define VTW (8*CPW)   // 1792
#define PLD 232       // P-LDS leading dim: 116 dwords = 20 mod 32 -> conflict-free frag reads
#define CLD 132       // LDS C-tile leading dim (4*66 dwords = 8 mod 32)

typedef __attribute__((ext_vector_type(8))) short bf16x8;
typedef __attribute__((ext_vector_type(4))) float f32x4;

typedef const __attribute__((address_space(1))) uint32_t guint;
typedef __attribute__((address_space(3))) uint32_t luint;

static __device__ __forceinline__ float bf2f(unsigned short u) {
  union { unsigned int i; float f; } v; v.i = ((unsigned int)u) << 16; return v.f;
}
static __device__ __forceinline__ unsigned short f2bf(float f) {
  __hip_bfloat16 h = __float2bfloat16(f);
  return __builtin_bit_cast(unsigned short, h);
}

// cast of Wqkv, Wproj only (x-cast is fused into the QKV GEMM A-staging)
__global__ void cast2_k(const float4* __restrict__ s1, ushort4* __restrict__ d1, int n1,
                        const float4* __restrict__ s2, ushort4* __restrict__ d2, int n2) {
  int nTot = n1 + n2;
  for (int i = blockIdx.x * blockDim.x + threadIdx.x; i < nTot; i += gridDim.x * blockDim.x) {
    const float4* s; ushort4* d; int off;
    if (i < n1) { s = s1; d = d1; off = i; }
    else { s = s2; d = d2; off = i - n1; }
    float4 f = s[off];
    ushort4 u;
    u.x = f2bf(f.x); u.y = f2bf(f.y); u.z = f2bf(f.z); u.w = f2bf(f.w);
    d[off] = u;
  }
}

// C = A[M,K] @ W[Nout,K]^T, MFMA 16x16x32 bf16, 128x128 tile, 4 waves (2x2).
// BK=64: two 32-wide (A,B) slab pairs per barrier-pair -> 32 MFMA/barrier (R9 core).
// MODE 0: A read as FP32 (x) and reg-staged with inline cvt into the SAME LDS
//         layout (fuses the old x-cast kernel); B via global_load_lds.
// MODE 1: A is bf16 (ao), both operands via global_load_lds (R9-exact).
template<int MODE>
__global__ __launch_bounds__(256) void gemm_k(
    const float* __restrict__ Af,              // MODE 0: x (f32)
    const __hip_bfloat16* __restrict__ Ab,     // MODE 1: ao (bf16)
    const __hip_bfloat16* __restrict__ W,
    int M, int K,
    __hip_bfloat16* __restrict__ qh, __hip_bfloat16* __restrict__ kh,
    __hip_bfloat16* __restrict__ vT, __hip_bfloat16* __restrict__ vcls,
    const float* __restrict__ bias, float* __restrict__ outp)
{
  __shared__ __align__(16) unsigned short shmem[128 * CLD];
  unsigned short* ls0 = shmem;
  unsigned short* ls1 = shmem + 4096;
  unsigned short* ls2 = shmem + 8192;
  unsigned short* ls3 = shmem + 12288;

  const int tid = threadIdx.x;
  const int lane = tid & 63, wid = tid >> 6;
  const int waveM = wid >> 1, waveN = wid & 1;

  const int gridN = gridDim.x;
  const int nwg = gridDim.x * gridDim.y;
  int bid = blockIdx.y * gridN + blockIdx.x;
  int q8 = nwg >> 3, r8 = nwg & 7;
  int xcd = bid & 7, lid = bid >> 3;
  int swz = (xcd < r8 ? xcd * (q8 + 1) : r8 * (q8 + 1) + (xcd - r8) * q8) + lid;
  const int mBase = (swz / gridN) * 128, nBase = (swz % gridN) * 128;

  const int l15 = lane & 15, lg = lane >> 4;
  f32x4 acc[4][4] = {};
  const int nkt = K >> 6;   // BK=64
  for (int kt = 0; kt < nkt; ++kt) {
#pragma unroll
    for (int s = 0; s < 2; ++s) {
      int seg = s * 256 + tid;
      int row = seg >> 2, ks = seg & 3;
      int arow = mBase + row; if (arow >= M) arow = M - 1;
      int brow = nBase + row;
      const __hip_bfloat16* wp = W + (size_t)brow * K + kt * 64 + ks * 8;
      __builtin_amdgcn_global_load_lds((guint*)wp,        (luint*)&ls1[seg * 8], 16, 0, 0);
      __builtin_amdgcn_global_load_lds((guint*)(wp + 32), (luint*)&ls3[seg * 8], 16, 0, 0);
      if (MODE == 0) {
        // reg-stage f32 A with inline cvt (fused x-cast); LDS layout identical
        const float* ap = Af + (size_t)arow * K + kt * 64 + ks * 8;
        float4 a0 = *reinterpret_cast<const float4*>(ap);
        float4 a1 = *reinterpret_cast<const float4*>(ap + 4);
        float4 a2 = *reinterpret_cast<const float4*>(ap + 32);
        float4 a3 = *reinterpret_cast<const float4*>(ap + 36);
        bf16x8 v0, v1;
        v0[0] = (short)f2bf(a0.x); v0[1] = (short)f2bf(a0.y);
        v0[2] = (short)f2bf(a0.z); v0[3] = (short)f2bf(a0.w);
        v0[4] = (short)f2bf(a1.x); v0[5] = (short)f2bf(a1.y);
        v0[6] = (short)f2bf(a1.z); v0[7] = (short)f2bf(a1.w);
        v1[0] = (short)f2bf(a2.x); v1[1] = (short)f2bf(a2.y);
        v1[2] = (short)f2bf(a2.z); v1[3] = (short)f2bf(a2.w);
        v1[4] = (short)f2bf(a3.x); v1[5] = (short)f2bf(a3.y);
        v1[6] = (short)f2bf(a3.z); v1[7] = (short)f2bf(a3.w);
        *reinterpret_cast<bf16x8*>(&ls0[seg * 8]) = v0;
        *reinterpret_cast<bf16x8*>(&ls2[seg * 8]) = v1;
      } else {
        const __hip_bfloat16* ap = Ab + (size_t)arow * K + kt * 64 + ks * 8;
        __builtin_amdgcn_global_load_lds((guint*)ap,        (luint*)&ls0[seg * 8], 16, 0, 0);
        __builtin_amdgcn_global_load_lds((guint*)(ap + 32), (luint*)&ls2[seg * 8], 16, 0, 0);
      }
    }
    __syncthreads();
    bf16x8 aF[4], bF[4], aG[4], bG[4];
#pragma unroll
    for (int i = 0; i < 4; ++i) {
      int ro = (waveM * 64 + i * 16 + l15) * 32 + lg * 8;
      int co = (waveN * 64 + i * 16 + l15) * 32 + lg * 8;
      aF[i] = *reinterpret_cast<const bf16x8*>(&ls0[ro]);
      bF[i] = *reinterpret_cast<const bf16x8*>(&ls1[co]);
      aG[i] = *reinterpret_cast<const bf16x8*>(&ls2[ro]);
      bG[i] = *reinterpret_cast<const bf16x8*>(&ls3[co]);
    }
#pragma unroll
    for (int mi = 0; mi < 4; ++mi)
#pragma unroll
      for (int ni = 0; ni < 4; ++ni) {
        acc[mi][ni] = __builtin_amdgcn_mfma_f32_16x16x32_bf16(aF[mi], bF[ni], acc[mi][ni], 0, 0, 0);
        acc[mi][ni] = __builtin_amdgcn_mfma_f32_16x16x32_bf16(aG[mi], bG[ni], acc[mi][ni], 0, 0, 0);
      }
    __syncthreads();
  }

  // Epilogue. C/D frag: col = lane&15, row = (lane>>4)*4 + reg  [m89-verified]
  if (MODE == 1) {
    const bool fullM = (mBase + 128 <= M);
#pragma unroll
    for (int mi = 0; mi < 4; ++mi)
#pragma unroll
      for (int ni = 0; ni < 4; ++ni)
#pragma unroll
        for (int r = 0; r < 4; ++r) {
          int grow = mBase + waveM * 64 + mi * 16 + lg * 4 + r;
          if (!fullM && grow >= M) continue;
          int gcol = nBase + waveN * 64 + ni * 16 + l15;
          outp[(size_t)grow * Dm + gcol] = acc[mi][ni][r] + bias[gcol];
        }
    return;
  }

  const int which = nBase / Dm;
  const int headBase = (nBase - which * Dm) >> 6;
  const float scl = (which == 0) ? 0.125f : 1.f;
  const bool fullM = (mBase + 128 <= M);

  if (fullM) {
    if (which < 2) {
#pragma unroll
      for (int mi = 0; mi < 4; ++mi)
#pragma unroll
        for (int ni = 0; ni < 4; ++ni)
#pragma unroll
          for (int r = 0; r < 4; ++r)
            shmem[(waveM * 64 + mi * 16 + lg * 4 + r) * CLD + (waveN * 64 + ni * 16 + l15)]
                = f2bf(acc[mi][ni][r] * scl);
      __syncthreads();
      __hip_bfloat16* dst = (which == 0) ? qh : kh;
      int row = tid >> 1, h = tid & 1;
      int grow = mBase + row;
      int b = grow / Nt, i = grow - b * Nt;
      const uint2* sp = reinterpret_cast<const uint2*>(&shmem[row * CLD + h * 64]);
      uint2* dp = reinterpret_cast<uint2*>(
          dst + ((size_t)(b * Hh + headBase + h) * Nt + i) * 64);
#pragma unroll
      for (int j = 0; j < 16; ++j) dp[j] = sp[j];
    } else {
#pragma unroll
      for (int mi = 0; mi < 4; ++mi)
#pragma unroll
        for (int ni = 0; ni < 4; ++ni)
#pragma unroll
          for (int r = 0; r < 4; ++r)
            shmem[(waveN * 64 + ni * 16 + l15) * CLD + (waveM * 64 + mi * 16 + lg * 4 + r)]
                = f2bf(acc[mi][ni][r]);
      __syncthreads();
      int lc = tid & 127, rhalf = tid >> 7;
      int h = lc >> 6, dc = lc & 63;
      int head = headBase + h;
#pragma unroll
      for (int g = 0; g < 8; ++g) {
        int row0 = rhalf * 64 + g * 8;
        int grow0 = mBase + row0;
        int b = grow0 / Nt, i0 = grow0 - b * Nt;
        const unsigned short* sp = &shmem[lc * CLD + row0];
        if (i0 >= 1 && i0 + 8 <= Nt) {
          int j0 = i0 - 1, cc = j0 / NC, key = j0 - cc * NC;
          if (key + 8 <= NC) {
            int bh = b * Hh + head;
            __hip_bfloat16* p = vT + ((size_t)bh * 64 + dc) * VTW + cc * CPW + key;
            if ((key & 1) == 0) {
              const unsigned int* s4 = reinterpret_cast<const unsigned int*>(sp);
              unsigned int* d4 = reinterpret_cast<unsigned int*>(p);
              d4[0] = s4[0]; d4[1] = s4[1]; d4[2] = s4[2]; d4[3] = s4[3];
            } else {
#pragma unroll
              for (int j = 0; j < 8; ++j)
                p[j] = __builtin_bit_cast(__hip_bfloat16, sp[j]);
            }
            continue;
          }
        }
#pragma unroll
        for (int j = 0; j < 8; ++j) {
          int grow = grow0 + j;
          int bb = grow / Nt, ii = grow - bb * Nt;
          int bh2 = bb * Hh + head;
          unsigned short val = sp[j];
          if (ii == 0) {
            vcls[bh2 * 64 + dc] = __builtin_bit_cast(__hip_bfloat16, val);
          } else {
            int jj = ii - 1, cc2 = jj / NC, k2 = jj - cc2 * NC;
            vT[((size_t)bh2 * 64 + dc) * VTW + cc2 * CPW + k2]
                = __builtin_bit_cast(__hip_bfloat16, val);
          }
        }
      }
    }
  } else {
#pragma unroll
    for (int mi = 0; mi < 4; ++mi)
#pragma unroll
      for (int ni = 0; ni < 4; ++ni)
#pragma unroll
        for (int r = 0; r < 4; ++r) {
          int grow = mBase + waveM * 64 + mi * 16 + lg * 4 + r;
          if (grow >= M) continue;
          int gcol = nBase + waveN * 64 + ni * 16 + l15;
          float v = acc[mi][ni][r];
          int b = grow / Nt, i = grow - b * Nt;
          int hcol = gcol - which * Dm;
          int head = hcol >> 6, dc = hcol & 63;
          int bh = b * Hh + head;
          if (which == 0) {
            qh[((size_t)bh * Nt + i) * 64 + dc] = __float2bfloat16(v * 0.125f);
          } else if (which == 1) {
            kh[((size_t)bh * Nt + i) * 64 + dc] = __float2bfloat16(v);
          } else {
            if (i == 0) vcls[bh * 64 + dc] = __float2bfloat16(v);
            else {
              int j = i - 1; int cc = j / NC, key = j - cc * NC;
              vT[((size_t)bh * 64 + dc) * VTW + cc * CPW + key] = __float2bfloat16(v);
            }
          }
        }
  }
}

// Merged attention (R16 structure + T5 setprio): 512 threads.
// Blocks 0..191 cls; 192.. chunk (8 waves, K/V/P in LDS).
__global__ __launch_bounds__(512, 2) void attn_k(
    const __hip_bfloat16* __restrict__ qh, const __hip_bfloat16* __restrict__ kh,
    const __hip_bfloat16* __restrict__ vT, const __hip_bfloat16* __restrict__ vcls,
    const float* __restrict__ x_mask, __hip_bfloat16* __restrict__ ao)
{
  __shared__ __align__(16) char smem[118784];
  // chunk: ldsK [0,26624) ldsV [26624,59392) ldsP [59392,118784)
  // cls:   sS [0,6400) qv [6400,6656) red [6656,8704)

  const int bidx = blockIdx.x;
  const int tid = threadIdx.x;

  if (bidx < BH) {
    // ---------------- cls path (512 threads) ----------------
    float* sS = reinterpret_cast<float*>(smem);
    float* qv = reinterpret_cast<float*>(smem + 6400);
    float* red = reinterpret_cast<float*>(smem + 6656);
    const int bh = bidx, b = bh / Hh, head = bh - b * Hh;
    if (tid < 64) qv[tid] = __bfloat162float(qh[((size_t)bh * Nt) * 64 + tid]);
    __syncthreads();
    float lmax = -1e30f;
    for (int j = tid; j < Nt; j += 512) {
      const __hip_bfloat16* kr = kh + ((size_t)bh * Nt + j) * 64;
      float dot = 0.f;
#pragma unroll
      for (int d0 = 0; d0 < 64; d0 += 8) {
        bf16x8 kv = *reinterpret_cast<const bf16x8*>(kr + d0);
#pragma unroll
        for (int i = 0; i < 8; ++i) dot += qv[d0 + i] * bf2f((unsigned short)kv[i]);
      }
      float s = dot + x_mask[b * Nt + j];
      sS[j] = s;
      lmax = fmaxf(lmax, s);
    }
    red[tid] = lmax; __syncthreads();
    for (int off = 256; off > 0; off >>= 1) {
      if (tid < off) red[tid] = fmaxf(red[tid], red[tid + off]);
      __syncthreads();
    }
    float m = red[0]; __syncthreads();
    float lsum = 0.f;
    for (int j = tid; j < Nt; j += 512) { float e = __expf(sS[j] - m); sS[j] = e; lsum += e; }
    red[tid] = lsum; __syncthreads();
    for (int off = 256; off > 0; off >>= 1) {
      if (tid < off) red[tid] += red[tid + off];
      __syncthreads();
    }
    float rden = 1.f / red[0]; __syncthreads();
    int dc = tid & 63, part = tid >> 6;
    float partial = 0.f;
    if (part == 0) partial = sS[0] * __bfloat162float(vcls[bh * 64 + dc]);
    {
      int base = 1 + part * NC;
      const __hip_bfloat16* vc2 = vT + ((size_t)bh * 64 + dc) * VTW + part * CPW;
      int key = 0;
      for (; key + 8 <= NC; key += 8) {
        bf16x8 vv = *reinterpret_cast<const bf16x8*>(vc2 + key);
#pragma unroll
        for (int i = 0; i < 8; ++i)
          partial += sS[base + key + i] * bf2f((unsigned short)vv[i]);
      }
      for (; key < NC; ++key)
        partial += sS[base + key] * __bfloat162float(vc2[key]);
    }
    red[tid] = partial; __syncthreads();
    if (tid < 64) {
      float o = 0.f;
#pragma unroll
      for (int k = 0; k < 8; ++k) o += red[tid + 64 * k];
      ao[((size_t)b * Nt) * Dm + head * 64 + dc] = __float2bfloat16(o * rden);
    }
    return;
  }

  // ---------------- chunk path (8 waves) ----------------
  __hip_bfloat16* ldsK = reinterpret_cast<__hip_bfloat16*>(smem);
  __hip_bfloat16* ldsV = reinterpret_cast<__hip_bfloat16*>(smem + 26624);
  __hip_bfloat16* ldsP = reinterpret_cast<__hip_bfloat16*>(smem + 59392);

  const int g = bidx - BH;
  const int bh = g >> 3, c = g & 7;
  const int b = bh / Hh, head = bh - b * Hh;
  const int lane = tid & 63, wid = tid >> 6;
  const int l15 = lane & 15, lg = lane >> 4;

  const int kbase = 1 + c * NC;

#pragma unroll
  for (int it = 0; it < 4; ++it) {
    int idx = it * 512 + tid;
    if (idx < 1664) {
      int row = idx >> 3, c16 = idx & 7;
      int token = kbase + row; if (token > Nt - 1) token = Nt - 1;
      __builtin_amdgcn_global_load_lds(
          (guint*)(kh + ((size_t)bh * Nt + token) * 64 + ((c16 ^ (row & 7)) * 8)),
          (luint*)&ldsK[idx * 8], 16, 0, 0);
    }
  }
#pragma unroll
  for (int it = 0; it < 4; ++it) {
    int idx = it * 512 + tid;
    if (idx < 1792) {
      int dc = idx / 28, u = idx - dc * 28;
      uint4 v = *reinterpret_cast<const uint4*>(
          vT + ((size_t)bh * 64 + dc) * VTW + c * CPW + u * 8);
      *reinterpret_cast<uint4*>(&ldsV[dc * 256 + ((u ^ (dc & 7)) * 8)]) = v;
    }
  }
  __syncthreads();

  __hip_bfloat16* myP = ldsP + wid * (16 * PLD);

  const __hip_bfloat16* kc = kh + (size_t)bh * Nt * 64;
  bf16x8 ck0 = *reinterpret_cast<const bf16x8*>(kc + lg * 8);
  bf16x8 ck1 = *reinterpret_cast<const bf16x8*>(kc + 32 + lg * 8);
  const float maskCls = x_mask[b * Nt];

  for (int rt = wid; rt < 13; rt += 8) {
    int qlrow = rt * 16 + l15;
    int qtok = 1 + c * NC + qlrow; if (qtok > Nt - 1) qtok = Nt - 1;
    const __hip_bfloat16* qp = qh + ((size_t)bh * Nt + qtok) * 64;
    bf16x8 aQ0 = *reinterpret_cast<const bf16x8*>(qp + lg * 8);
    bf16x8 aQ1 = *reinterpret_cast<const bf16x8*>(qp + 32 + lg * 8);

    float pc0 = 0.f;
#pragma unroll
    for (int i = 0; i < 8; ++i)
      pc0 += bf2f((unsigned short)aQ0[i]) * bf2f((unsigned short)ck0[i])
           + bf2f((unsigned short)aQ1[i]) * bf2f((unsigned short)ck1[i]);
    pc0 += __shfl_xor(pc0, 16);
    pc0 += __shfl_xor(pc0, 32);
    pc0 += maskCls;

    f32x4 S[13];
    float mv[13];
    __builtin_amdgcn_s_setprio(1);
#define LD_MM(i) { \
    int row = (i) * 16 + l15; \
    bf16x8 kb0 = *reinterpret_cast<const bf16x8*>(&ldsK[row * 64 + ((lg ^ (l15 & 7)) * 8)]); \
    bf16x8 kb1 = *reinterpret_cast<const bf16x8*>(&ldsK[row * 64 + (((4 + lg) ^ (l15 & 7)) * 8)]); \
    mv[i] = (row < NC) ? x_mask[b * Nt + kbase + row] : -1e30f; \
    f32x4 sa = {}; \
    sa = __builtin_amdgcn_mfma_f32_16x16x32_bf16(aQ0, kb0, sa, 0, 0, 0); \
    sa = __builtin_amdgcn_mfma_f32_16x16x32_bf16(aQ1, kb1, sa, 0, 0, 0); \
    S[i][0] = sa[0] + mv[i]; S[i][1] = sa[1] + mv[i]; \
    S[i][2] = sa[2] + mv[i]; S[i][3] = sa[3] + mv[i]; }
    LD_MM(0) LD_MM(1) LD_MM(2) LD_MM(3) LD_MM(4) LD_MM(5) LD_MM(6)
    LD_MM(7) LD_MM(8) LD_MM(9) LD_MM(10) LD_MM(11) LD_MM(12)
#undef LD_MM
    __builtin_amdgcn_s_setprio(0);

    float pcls[4], rden[4];
#pragma unroll
    for (int r = 0; r < 4; ++r) {
      float m = -1e30f;
#pragma unroll
      for (int nt = 0; nt < 13; ++nt) m = fmaxf(m, S[nt][r]);
      m = fmaxf(m, __shfl_xor(m, 1));
      m = fmaxf(m, __shfl_xor(m, 2));
      m = fmaxf(m, __shfl_xor(m, 4));
      m = fmaxf(m, __shfl_xor(m, 8));
      float sc = __shfl(pc0, lg * 4 + r);
      m = fmaxf(m, sc);
      float sum = 0.f;
#pragma unroll
      for (int nt = 0; nt < 13; ++nt) { float e = __expf(S[nt][r] - m); S[nt][r] = e; sum += e; }
      sum += __shfl_xor(sum, 1);
      sum += __shfl_xor(sum, 2);
      sum += __shfl_xor(sum, 4);
      sum += __shfl_xor(sum, 8);
      float pc = __expf(sc - m);
      pcls[r] = pc;
      rden[r] = 1.f / (sum + pc);
    }

#pragma unroll
    for (int nt = 0; nt < 13; ++nt)
#pragma unroll
      for (int r = 0; r < 4; ++r)
        myP[(lg * 4 + r) * PLD + nt * 16 + l15] = __float2bfloat16(S[nt][r]);
#pragma unroll
    for (int r = 0; r < 4; ++r)
      myP[l15 * PLD + 208 + lg * 4 + r] = __float2bfloat16(0.f);
    asm volatile("s_waitcnt lgkmcnt(0)" ::: "memory");
    __builtin_amdgcn_sched_barrier(0);

    f32x4 O[4] = {};
    __builtin_amdgcn_s_setprio(1);
#define PVK(kt) { \
    bf16x8 aP = *reinterpret_cast<const bf16x8*>(&myP[l15 * PLD + (kt) * 32 + lg * 8]); \
    { int dc = 0 * 16 + l15; bf16x8 bV = *reinterpret_cast<const bf16x8*>(&ldsV[dc * 256 + ((((kt) * 4 + lg) ^ (l15 & 7)) * 8)]); \
      O[0] = __builtin_amdgcn_mfma_f32_16x16x32_bf16(aP, bV, O[0], 0, 0, 0); } \
    { int dc = 1 * 16 + l15; bf16x8 bV = *reinterpret_cast<const bf16x8*>(&ldsV[dc * 256 + ((((kt) * 4 + lg) ^ (l15 & 7)) * 8)]); \
      O[1] = __builtin_amdgcn_mfma_f32_16x16x32_bf16(aP, bV, O[1], 0, 0, 0); } \
    { int dc = 2 * 16 + l15; bf16x8 bV = *reinterpret_cast<const bf16x8*>(&ldsV[dc * 256 + ((((kt) * 4 + lg) ^ (l15 & 7)) * 8)]); \
      O[2] = __builtin_amdgcn_mfma_f32_16x16x32_bf16(aP, bV, O[2], 0, 0, 0); } \
    { int dc = 3 * 16 + l15; bf16x8 bV = *reinterpret_cast<const bf16x8*>(&ldsV[dc * 256 + ((((kt) * 4 + lg) ^ (l15 & 7)) * 8)]); \
      O[3] = __builtin_amdgcn_mfma_f32_16x16x32_bf16(aP, bV, O[3], 0, 0, 0); } }
    PVK(0) PVK(1) PVK(2) PVK(3) PVK(4) PVK(5) PVK(6)
#undef PVK
    __builtin_amdgcn_s_setprio(0);

#pragma unroll
    for (int ni = 0; ni < 4; ++ni) {
      int dc = ni * 16 + l15;
      float vc = __bfloat162float(vcls[bh * 64 + dc]);
#pragma unroll
      for (int r = 0; r < 4; ++r) {
        int lrow = rt * 16 + lg * 4 + r;
        if (lrow < NC) {
          float o = (O[ni][r] + pcls[r] * vc) * rden[r];
          int tok = 1 + c * NC + lrow;
          ao[((size_t)b * Nt + tok) * Dm + head * 64 + dc] = __float2bfloat16(o);
        }
      }
    }
  }
}

extern "C" void kernel_launch(void* const* d_in, const int* in_sizes, int n_in,
                              void* d_out, int out_size, void* d_ws, size_t ws_size,
                              hipStream_t stream) {
  const float* x     = (const float*)d_in[0];
  const float* xmask = (const float*)d_in[1];
  const float* wqkv  = (const float*)d_in[2];
  const float* wproj = (const float*)d_in[3];
  const float* bproj = (const float*)d_in[4];
  float* outp = (float*)d_out;

  char* ws = (char*)d_ws;
  size_t off = 0;
  auto alloc = [&](size_t bytes) {
    char* p = ws + off;
    off += (bytes + 255) & ~(size_t)255;
    return p;
  };
  __hip_bfloat16* ao     = (__hip_bfloat16*)alloc((size_t)Mr * Dm * 2);   // attn out (was xb)
  __hip_bfloat16* wqkvb  = (__hip_bfloat16*)alloc((size_t)3 * Dm * Dm * 2);
  __hip_bfloat16* wprojb = (__hip_bfloat16*)alloc((size_t)Dm * Dm * 2);
  __hip_bfloat16* qh     = (__hip_bfloat16*)alloc((size_t)BH * Nt * 64 * 2);
  __hip_bfloat16* kh     = (__hip_bfloat16*)alloc((size_t)BH * Nt * 64 * 2);
  __hip_bfloat16* vT     = (__hip_bfloat16*)alloc((size_t)BH * 64 * VTW * 2);
  __hip_bfloat16* vcls   = (__hip_bfloat16*)alloc((size_t)BH * 64 * 2);

  cast2_k<<<512, 256, 0, stream>>>((const float4*)wqkv, (ushort4*)wqkvb, 3 * Dm * Dm / 4,
                                   (const float4*)wproj, (ushort4*)wprojb, Dm * Dm / 4);

  // QKV projection: x(f32) @ Wqkv^T, cast fused into A-staging
  gemm_k<0><<<dim3(18, 197), 256, 0, stream>>>(x, nullptr, wqkvb, Mr, Dm,
                                               qh, kh, vT, vcls, nullptr, nullptr);

  // merged cls + chunk attention (512 threads)
  attn_k<<<BH + BH * Ff, 512, 0, stream>>>(qh, kh, vT, vcls, xmask, ao);

  // output projection + bias: ao(bf16) @ Wproj^T -> f32 d_out
  gemm_k<1><<<dim3(6, 197), 256, 0, stream>>>(nullptr, ao, wprojb, Mr, Dm,
                                              nullptr, nullptr, nullptr, nullptr, bproj, outp);
}

// Round 20
// 300.150 us; speedup vs baseline: 1.0489x; 1.0489x over previous
//
#include <hip/hip_runtime.h>
#include <hip/hip_bf16.h>
#include <stdint.h>

// Problem shape (fixed by setup_inputs)
#define Hh 12
#define Dm 768
#define Bb 16
#define Nt 1569       // 1 + 8*196 tokens
#define Ff 8
#define NC 196        // chunk length
#define BH 192        // B*H
#define Mr 25104      // B*Nt rows
#define CPW 224       // per-chunk padded width in vT (multiple of 32)
#define VTW (8*CPW)   // 1792
#define PLD 232       // P-LDS leading dim: 116 dwords = 20 mod 32 -> conflict-free frag reads
#define CLD 132       // LDS C-tile leading dim (4*66 dwords = 8 mod 32)

typedef __attribute__((ext_vector_type(8))) short bf16x8;
typedef __attribute__((ext_vector_type(4))) float f32x4;

typedef const __attribute__((address_space(1))) uint32_t guint;
typedef __attribute__((address_space(3))) uint32_t luint;

static __device__ __forceinline__ float bf2f(unsigned short u) {
  union { unsigned int i; float f; } v; v.i = ((unsigned int)u) << 16; return v.f;
}
static __device__ __forceinline__ unsigned short f2bf(float f) {
  __hip_bfloat16 h = __float2bfloat16(f);
  return __builtin_bit_cast(unsigned short, h);
}

// fused cast of x, Wqkv, Wproj (separate kernel: pure-BW, ~22 us; fusing into
// GEMM A-staging regressed QKV 143->181 in R19 — DMA staging beats reg-staging)
__global__ void cast3_k(const float4* __restrict__ s0, ushort4* __restrict__ d0, int n0,
                        const float4* __restrict__ s1, ushort4* __restrict__ d1, int n1,
                        const float4* __restrict__ s2, ushort4* __restrict__ d2, int n2) {
  int nTot = n0 + n1 + n2;
  for (int i = blockIdx.x * blockDim.x + threadIdx.x; i < nTot; i += gridDim.x * blockDim.x) {
    const float4* s; ushort4* d; int off;
    if (i < n0) { s = s0; d = d0; off = i; }
    else if (i < n0 + n1) { s = s1; d = d1; off = i - n0; }
    else { s = s2; d = d2; off = i - n0 - n1; }
    float4 f = s[off];
    ushort4 u;
    u.x = f2bf(f.x); u.y = f2bf(f.y); u.z = f2bf(f.z); u.w = f2bf(f.w);
    d[off] = u;
  }
}

// C = A[M,K] @ W[Nout,K]^T, MFMA 16x16x32 bf16, 128x128 tile, 4 waves (2x2).
// BK=64: two 32-wide (A,B) slab pairs staged per barrier-pair -> 32 MFMA/barrier.
// R9-EXACT: measured floor for this K=768 shape (143 us QKV). Seven variants
// (dbuf, 256^2 coarse+phased, 3-buf, 128x256 widen, cast-fused A) all regressed.
template<int MODE>
__global__ __launch_bounds__(256) void gemm_k(
    const __hip_bfloat16* __restrict__ A,
    const __hip_bfloat16* __restrict__ W,
    int M, int K,
    __hip_bfloat16* __restrict__ qh, __hip_bfloat16* __restrict__ kh,
    __hip_bfloat16* __restrict__ vT, __hip_bfloat16* __restrict__ vcls,
    const float* __restrict__ bias, float* __restrict__ outp)
{
  __shared__ __align__(16) unsigned short shmem[128 * CLD];
  unsigned short* ls0 = shmem;
  unsigned short* ls1 = shmem + 4096;
  unsigned short* ls2 = shmem + 8192;
  unsigned short* ls3 = shmem + 12288;

  const int tid = threadIdx.x;
  const int lane = tid & 63, wid = tid >> 6;
  const int waveM = wid >> 1, waveN = wid & 1;

  const int gridN = gridDim.x;
  const int nwg = gridDim.x * gridDim.y;
  int bid = blockIdx.y * gridN + blockIdx.x;
  int q8 = nwg >> 3, r8 = nwg & 7;
  int xcd = bid & 7, lid = bid >> 3;
  int swz = (xcd < r8 ? xcd * (q8 + 1) : r8 * (q8 + 1) + (xcd - r8) * q8) + lid;
  const int mBase = (swz / gridN) * 128, nBase = (swz % gridN) * 128;

  const int l15 = lane & 15, lg = lane >> 4;
  f32x4 acc[4][4] = {};
  const int nkt = K >> 6;   // BK=64
  for (int kt = 0; kt < nkt; ++kt) {
#pragma unroll
    for (int s = 0; s < 2; ++s) {
      int seg = s * 256 + tid;
      int row = seg >> 2, ks = seg & 3;
      int arow = mBase + row; if (arow >= M) arow = M - 1;
      int brow = nBase + row;
      const __hip_bfloat16* ap = A + (size_t)arow * K + kt * 64 + ks * 8;
      const __hip_bfloat16* wp = W + (size_t)brow * K + kt * 64 + ks * 8;
      __builtin_amdgcn_global_load_lds((guint*)ap,        (luint*)&ls0[seg * 8], 16, 0, 0);
      __builtin_amdgcn_global_load_lds((guint*)wp,        (luint*)&ls1[seg * 8], 16, 0, 0);
      __builtin_amdgcn_global_load_lds((guint*)(ap + 32), (luint*)&ls2[seg * 8], 16, 0, 0);
      __builtin_amdgcn_global_load_lds((guint*)(wp + 32), (luint*)&ls3[seg * 8], 16, 0, 0);
    }
    __syncthreads();
    bf16x8 aF[4], bF[4], aG[4], bG[4];
#pragma unroll
    for (int i = 0; i < 4; ++i) {
      int ro = (waveM * 64 + i * 16 + l15) * 32 + lg * 8;
      int co = (waveN * 64 + i * 16 + l15) * 32 + lg * 8;
      aF[i] = *reinterpret_cast<const bf16x8*>(&ls0[ro]);
      bF[i] = *reinterpret_cast<const bf16x8*>(&ls1[co]);
      aG[i] = *reinterpret_cast<const bf16x8*>(&ls2[ro]);
      bG[i] = *reinterpret_cast<const bf16x8*>(&ls3[co]);
    }
#pragma unroll
    for (int mi = 0; mi < 4; ++mi)
#pragma unroll
      for (int ni = 0; ni < 4; ++ni) {
        acc[mi][ni] = __builtin_amdgcn_mfma_f32_16x16x32_bf16(aF[mi], bF[ni], acc[mi][ni], 0, 0, 0);
        acc[mi][ni] = __builtin_amdgcn_mfma_f32_16x16x32_bf16(aG[mi], bG[ni], acc[mi][ni], 0, 0, 0);
      }
    __syncthreads();
  }

  // Epilogue. C/D frag: col = lane&15, row = (lane>>4)*4 + reg  [m89-verified]
  if (MODE == 1) {
    const bool fullM = (mBase + 128 <= M);
#pragma unroll
    for (int mi = 0; mi < 4; ++mi)
#pragma unroll
      for (int ni = 0; ni < 4; ++ni)
#pragma unroll
        for (int r = 0; r < 4; ++r) {
          int grow = mBase + waveM * 64 + mi * 16 + lg * 4 + r;
          if (!fullM && grow >= M) continue;
          int gcol = nBase + waveN * 64 + ni * 16 + l15;
          outp[(size_t)grow * Dm + gcol] = acc[mi][ni][r] + bias[gcol];
        }
    return;
  }

  const int which = nBase / Dm;
  const int headBase = (nBase - which * Dm) >> 6;
  const float scl = (which == 0) ? 0.125f : 1.f;
  const bool fullM = (mBase + 128 <= M);

  if (fullM) {
    if (which < 2) {
#pragma unroll
      for (int mi = 0; mi < 4; ++mi)
#pragma unroll
        for (int ni = 0; ni < 4; ++ni)
#pragma unroll
          for (int r = 0; r < 4; ++r)
            shmem[(waveM * 64 + mi * 16 + lg * 4 + r) * CLD + (waveN * 64 + ni * 16 + l15)]
                = f2bf(acc[mi][ni][r] * scl);
      __syncthreads();
      __hip_bfloat16* dst = (which == 0) ? qh : kh;
      int row = tid >> 1, h = tid & 1;
      int grow = mBase + row;
      int b = grow / Nt, i = grow - b * Nt;
      const uint2* sp = reinterpret_cast<const uint2*>(&shmem[row * CLD + h * 64]);
      uint2* dp = reinterpret_cast<uint2*>(
          dst + ((size_t)(b * Hh + headBase + h) * Nt + i) * 64);
#pragma unroll
      for (int j = 0; j < 16; ++j) dp[j] = sp[j];
    } else {
#pragma unroll
      for (int mi = 0; mi < 4; ++mi)
#pragma unroll
        for (int ni = 0; ni < 4; ++ni)
#pragma unroll
          for (int r = 0; r < 4; ++r)
            shmem[(waveN * 64 + ni * 16 + l15) * CLD + (waveM * 64 + mi * 16 + lg * 4 + r)]
                = f2bf(acc[mi][ni][r]);
      __syncthreads();
      int lc = tid & 127, rhalf = tid >> 7;
      int h = lc >> 6, dc = lc & 63;
      int head = headBase + h;
#pragma unroll
      for (int g = 0; g < 8; ++g) {
        int row0 = rhalf * 64 + g * 8;
        int grow0 = mBase + row0;
        int b = grow0 / Nt, i0 = grow0 - b * Nt;
        const unsigned short* sp = &shmem[lc * CLD + row0];
        if (i0 >= 1 && i0 + 8 <= Nt) {
          int j0 = i0 - 1, cc = j0 / NC, key = j0 - cc * NC;
          if (key + 8 <= NC) {
            int bh = b * Hh + head;
            __hip_bfloat16* p = vT + ((size_t)bh * 64 + dc) * VTW + cc * CPW + key;
            if ((key & 1) == 0) {
              const unsigned int* s4 = reinterpret_cast<const unsigned int*>(sp);
              unsigned int* d4 = reinterpret_cast<unsigned int*>(p);
              d4[0] = s4[0]; d4[1] = s4[1]; d4[2] = s4[2]; d4[3] = s4[3];
            } else {
#pragma unroll
              for (int j = 0; j < 8; ++j)
                p[j] = __builtin_bit_cast(__hip_bfloat16, sp[j]);
            }
            continue;
          }
        }
#pragma unroll
        for (int j = 0; j < 8; ++j) {
          int grow = grow0 + j;
          int bb = grow / Nt, ii = grow - bb * Nt;
          int bh2 = bb * Hh + head;
          unsigned short val = sp[j];
          if (ii == 0) {
            vcls[bh2 * 64 + dc] = __builtin_bit_cast(__hip_bfloat16, val);
          } else {
            int jj = ii - 1, cc2 = jj / NC, k2 = jj - cc2 * NC;
            vT[((size_t)bh2 * 64 + dc) * VTW + cc2 * CPW + k2]
                = __builtin_bit_cast(__hip_bfloat16, val);
          }
        }
      }
    }
  } else {
#pragma unroll
    for (int mi = 0; mi < 4; ++mi)
#pragma unroll
      for (int ni = 0; ni < 4; ++ni)
#pragma unroll
        for (int r = 0; r < 4; ++r) {
          int grow = mBase + waveM * 64 + mi * 16 + lg * 4 + r;
          if (grow >= M) continue;
          int gcol = nBase + waveN * 64 + ni * 16 + l15;
          float v = acc[mi][ni][r];
          int b = grow / Nt, i = grow - b * Nt;
          int hcol = gcol - which * Dm;
          int head = hcol >> 6, dc = hcol & 63;
          int bh = b * Hh + head;
          if (which == 0) {
            qh[((size_t)bh * Nt + i) * 64 + dc] = __float2bfloat16(v * 0.125f);
          } else if (which == 1) {
            kh[((size_t)bh * Nt + i) * 64 + dc] = __float2bfloat16(v);
          } else {
            if (i == 0) vcls[bh * 64 + dc] = __float2bfloat16(v);
            else {
              int j = i - 1; int cc = j / NC, key = j - cc * NC;
              vT[((size_t)bh * 64 + dc) * VTW + cc * CPW + key] = __float2bfloat16(v);
            }
          }
        }
  }
}

// Merged attention (R16-exact, session best): 512 threads.
// Blocks 0..191 cls; 192.. chunk (8 waves, K/V/P in LDS, 118.8 KB).
__global__ __launch_bounds__(512, 2) void attn_k(
    const __hip_bfloat16* __restrict__ qh, const __hip_bfloat16* __restrict__ kh,
    const __hip_bfloat16* __restrict__ vT, const __hip_bfloat16* __restrict__ vcls,
    const float* __restrict__ x_mask, __hip_bfloat16* __restrict__ ao)
{
  __shared__ __align__(16) char smem[118784];
  // chunk: ldsK [0,26624) ldsV [26624,59392) ldsP [59392,118784)
  // cls:   sS [0,6400) qv [6400,6656) red [6656,8704)

  const int bidx = blockIdx.x;
  const int tid = threadIdx.x;

  if (bidx < BH) {
    // ---------------- cls path (512 threads) ----------------
    float* sS = reinterpret_cast<float*>(smem);
    float* qv = reinterpret_cast<float*>(smem + 6400);
    float* red = reinterpret_cast<float*>(smem + 6656);
    const int bh = bidx, b = bh / Hh, head = bh - b * Hh;
    if (tid < 64) qv[tid] = __bfloat162float(qh[((size_t)bh * Nt) * 64 + tid]);
    __syncthreads();
    float lmax = -1e30f;
    for (int j = tid; j < Nt; j += 512) {
      const __hip_bfloat16* kr = kh + ((size_t)bh * Nt + j) * 64;
      float dot = 0.f;
#pragma unroll
      for (int d0 = 0; d0 < 64; d0 += 8) {
        bf16x8 kv = *reinterpret_cast<const bf16x8*>(kr + d0);
#pragma unroll
        for (int i = 0; i < 8; ++i) dot += qv[d0 + i] * bf2f((unsigned short)kv[i]);
      }
      float s = dot + x_mask[b * Nt + j];
      sS[j] = s;
      lmax = fmaxf(lmax, s);
    }
    red[tid] = lmax; __syncthreads();
    for (int off = 256; off > 0; off >>= 1) {
      if (tid < off) red[tid] = fmaxf(red[tid], red[tid + off]);
      __syncthreads();
    }
    float m = red[0]; __syncthreads();
    float lsum = 0.f;
    for (int j = tid; j < Nt; j += 512) { float e = __expf(sS[j] - m); sS[j] = e; lsum += e; }
    red[tid] = lsum; __syncthreads();
    for (int off = 256; off > 0; off >>= 1) {
      if (tid < off) red[tid] += red[tid + off];
      __syncthreads();
    }
    float rden = 1.f / red[0]; __syncthreads();
    int dc = tid & 63, part = tid >> 6;
    float partial = 0.f;
    if (part == 0) partial = sS[0] * __bfloat162float(vcls[bh * 64 + dc]);
    {
      int base = 1 + part * NC;
      const __hip_bfloat16* vc2 = vT + ((size_t)bh * 64 + dc) * VTW + part * CPW;
      int key = 0;
      for (; key + 8 <= NC; key += 8) {
        bf16x8 vv = *reinterpret_cast<const bf16x8*>(vc2 + key);
#pragma unroll
        for (int i = 0; i < 8; ++i)
          partial += sS[base + key + i] * bf2f((unsigned short)vv[i]);
      }
      for (; key < NC; ++key)
        partial += sS[base + key] * __bfloat162float(vc2[key]);
    }
    red[tid] = partial; __syncthreads();
    if (tid < 64) {
      float o = 0.f;
#pragma unroll
      for (int k = 0; k < 8; ++k) o += red[tid + 64 * k];
      ao[((size_t)b * Nt) * Dm + head * 64 + dc] = __float2bfloat16(o * rden);
    }
    return;
  }

  // ---------------- chunk path (8 waves) ----------------
  __hip_bfloat16* ldsK = reinterpret_cast<__hip_bfloat16*>(smem);
  __hip_bfloat16* ldsV = reinterpret_cast<__hip_bfloat16*>(smem + 26624);
  __hip_bfloat16* ldsP = reinterpret_cast<__hip_bfloat16*>(smem + 59392);

  const int g = bidx - BH;
  const int bh = g >> 3, c = g & 7;
  const int b = bh / Hh, head = bh - b * Hh;
  const int lane = tid & 63, wid = tid >> 6;
  const int l15 = lane & 15, lg = lane >> 4;

  const int kbase = 1 + c * NC;

#pragma unroll
  for (int it = 0; it < 4; ++it) {
    int idx = it * 512 + tid;
    if (idx < 1664) {
      int row = idx >> 3, c16 = idx & 7;
      int token = kbase + row; if (token > Nt - 1) token = Nt - 1;
      __builtin_amdgcn_global_load_lds(
          (guint*)(kh + ((size_t)bh * Nt + token) * 64 + ((c16 ^ (row & 7)) * 8)),
          (luint*)&ldsK[idx * 8], 16, 0, 0);
    }
  }
#pragma unroll
  for (int it = 0; it < 4; ++it) {
    int idx = it * 512 + tid;
    if (idx < 1792) {
      int dc = idx / 28, u = idx - dc * 28;
      uint4 v = *reinterpret_cast<const uint4*>(
          vT + ((size_t)bh * 64 + dc) * VTW + c * CPW + u * 8);
      *reinterpret_cast<uint4*>(&ldsV[dc * 256 + ((u ^ (dc & 7)) * 8)]) = v;
    }
  }
  __syncthreads();

  __hip_bfloat16* myP = ldsP + wid * (16 * PLD);

  const __hip_bfloat16* kc = kh + (size_t)bh * Nt * 64;
  bf16x8 ck0 = *reinterpret_cast<const bf16x8*>(kc + lg * 8);
  bf16x8 ck1 = *reinterpret_cast<const bf16x8*>(kc + 32 + lg * 8);
  const float maskCls = x_mask[b * Nt];

  for (int rt = wid; rt < 13; rt += 8) {
    int qlrow = rt * 16 + l15;
    int qtok = 1 + c * NC + qlrow; if (qtok > Nt - 1) qtok = Nt - 1;
    const __hip_bfloat16* qp = qh + ((size_t)bh * Nt + qtok) * 64;
    bf16x8 aQ0 = *reinterpret_cast<const bf16x8*>(qp + lg * 8);
    bf16x8 aQ1 = *reinterpret_cast<const bf16x8*>(qp + 32 + lg * 8);

    float pc0 = 0.f;
#pragma unroll
    for (int i = 0; i < 8; ++i)
      pc0 += bf2f((unsigned short)aQ0[i]) * bf2f((unsigned short)ck0[i])
           + bf2f((unsigned short)aQ1[i]) * bf2f((unsigned short)ck1[i]);
    pc0 += __shfl_xor(pc0, 16);
    pc0 += __shfl_xor(pc0, 32);
    pc0 += maskCls;

    f32x4 S[13];
    float mv[13];
#define LD_MM(i) { \
    int row = (i) * 16 + l15; \
    bf16x8 kb0 = *reinterpret_cast<const bf16x8*>(&ldsK[row * 64 + ((lg ^ (l15 & 7)) * 8)]); \
    bf16x8 kb1 = *reinterpret_cast<const bf16x8*>(&ldsK[row * 64 + (((4 + lg) ^ (l15 & 7)) * 8)]); \
    mv[i] = (row < NC) ? x_mask[b * Nt + kbase + row] : -1e30f; \
    f32x4 sa = {}; \
    sa = __builtin_amdgcn_mfma_f32_16x16x32_bf16(aQ0, kb0, sa, 0, 0, 0); \
    sa = __builtin_amdgcn_mfma_f32_16x16x32_bf16(aQ1, kb1, sa, 0, 0, 0); \
    S[i][0] = sa[0] + mv[i]; S[i][1] = sa[1] + mv[i]; \
    S[i][2] = sa[2] + mv[i]; S[i][3] = sa[3] + mv[i]; }
    LD_MM(0) LD_MM(1) LD_MM(2) LD_MM(3) LD_MM(4) LD_MM(5) LD_MM(6)
    LD_MM(7) LD_MM(8) LD_MM(9) LD_MM(10) LD_MM(11) LD_MM(12)
#undef LD_MM

    float pcls[4], rden[4];
#pragma unroll
    for (int r = 0; r < 4; ++r) {
      float m = -1e30f;
#pragma unroll
      for (int nt = 0; nt < 13; ++nt) m = fmaxf(m, S[nt][r]);
      m = fmaxf(m, __shfl_xor(m, 1));
      m = fmaxf(m, __shfl_xor(m, 2));
      m = fmaxf(m, __shfl_xor(m, 4));
      m = fmaxf(m, __shfl_xor(m, 8));
      float sc = __shfl(pc0, lg * 4 + r);
      m = fmaxf(m, sc);
      float sum = 0.f;
#pragma unroll
      for (int nt = 0; nt < 13; ++nt) { float e = __expf(S[nt][r] - m); S[nt][r] = e; sum += e; }
      sum += __shfl_xor(sum, 1);
      sum += __shfl_xor(sum, 2);
      sum += __shfl_xor(sum, 4);
      sum += __shfl_xor(sum, 8);
      float pc = __expf(sc - m);
      pcls[r] = pc;
      rden[r] = 1.f / (sum + pc);
    }

#pragma unroll
    for (int nt = 0; nt < 13; ++nt)
#pragma unroll
      for (int r = 0; r < 4; ++r)
        myP[(lg * 4 + r) * PLD + nt * 16 + l15] = __float2bfloat16(S[nt][r]);
#pragma unroll
    for (int r = 0; r < 4; ++r)
      myP[l15 * PLD + 208 + lg * 4 + r] = __float2bfloat16(0.f);
    asm volatile("s_waitcnt lgkmcnt(0)" ::: "memory");   // wave-local write->read fence
    __builtin_amdgcn_sched_barrier(0);

    f32x4 O[4] = {};
#define PVK(kt) { \
    bf16x8 aP = *reinterpret_cast<const bf16x8*>(&myP[l15 * PLD + (kt) * 32 + lg * 8]); \
    { int dc = 0 * 16 + l15; bf16x8 bV = *reinterpret_cast<const bf16x8*>(&ldsV[dc * 256 + ((((kt) * 4 + lg) ^ (l15 & 7)) * 8)]); \
      O[0] = __builtin_amdgcn_mfma_f32_16x16x32_bf16(aP, bV, O[0], 0, 0, 0); } \
    { int dc = 1 * 16 + l15; bf16x8 bV = *reinterpret_cast<const bf16x8*>(&ldsV[dc * 256 + ((((kt) * 4 + lg) ^ (l15 & 7)) * 8)]); \
      O[1] = __builtin_amdgcn_mfma_f32_16x16x32_bf16(aP, bV, O[1], 0, 0, 0); } \
    { int dc = 2 * 16 + l15; bf16x8 bV = *reinterpret_cast<const bf16x8*>(&ldsV[dc * 256 + ((((kt) * 4 + lg) ^ (l15 & 7)) * 8)]); \
      O[2] = __builtin_amdgcn_mfma_f32_16x16x32_bf16(aP, bV, O[2], 0, 0, 0); } \
    { int dc = 3 * 16 + l15; bf16x8 bV = *reinterpret_cast<const bf16x8*>(&ldsV[dc * 256 + ((((kt) * 4 + lg) ^ (l15 & 7)) * 8)]); \
      O[3] = __builtin_amdgcn_mfma_f32_16x16x32_bf16(aP, bV, O[3], 0, 0, 0); } }
    PVK(0) PVK(1) PVK(2) PVK(3) PVK(4) PVK(5) PVK(6)
#undef PVK

#pragma unroll
    for (int ni = 0; ni < 4; ++ni) {
      int dc = ni * 16 + l15;
      float vc = __bfloat162float(vcls[bh * 64 + dc]);
#pragma unroll
      for (int r = 0; r < 4; ++r) {
        int lrow = rt * 16 + lg * 4 + r;
        if (lrow < NC) {
          float o = (O[ni][r] + pcls[r] * vc) * rden[r];
          int tok = 1 + c * NC + lrow;
          ao[((size_t)b * Nt + tok) * Dm + head * 64 + dc] = __float2bfloat16(o);
        }
      }
    }
  }
}

extern "C" void kernel_launch(void* const* d_in, const int* in_sizes, int n_in,
                              void* d_out, int out_size, void* d_ws, size_t ws_size,
                              hipStream_t stream) {
  const float* x     = (const float*)d_in[0];
  const float* xmask = (const float*)d_in[1];
  const float* wqkv  = (const float*)d_in[2];
  const float* wproj = (const float*)d_in[3];
  const float* bproj = (const float*)d_in[4];
  float* outp = (float*)d_out;

  char* ws = (char*)d_ws;
  size_t off = 0;
  auto alloc = [&](size_t bytes) {
    char* p = ws + off;
    off += (bytes + 255) & ~(size_t)255;
    return p;
  };
  __hip_bfloat16* xb     = (__hip_bfloat16*)alloc((size_t)Mr * Dm * 2);
  __hip_bfloat16* wqkvb  = (__hip_bfloat16*)alloc((size_t)3 * Dm * Dm * 2);
  __hip_bfloat16* wprojb = (__hip_bfloat16*)alloc((size_t)Dm * Dm * 2);
  __hip_bfloat16* qh     = (__hip_bfloat16*)alloc((size_t)BH * Nt * 64 * 2);
  __hip_bfloat16* kh     = (__hip_bfloat16*)alloc((size_t)BH * Nt * 64 * 2);
  __hip_bfloat16* vT     = (__hip_bfloat16*)alloc((size_t)BH * 64 * VTW * 2);
  __hip_bfloat16* vcls   = (__hip_bfloat16*)alloc((size_t)BH * 64 * 2);
  __hip_bfloat16* ao = xb;   // alias: xb dead after QKV GEMM

  cast3_k<<<2048, 256, 0, stream>>>((const float4*)x, (ushort4*)xb, Mr * Dm / 4,
                                    (const float4*)wqkv, (ushort4*)wqkvb, 3 * Dm * Dm / 4,
                                    (const float4*)wproj, (ushort4*)wprojb, Dm * Dm / 4);

  // QKV projection: [25104,768] @ [2304,768]^T
  gemm_k<0><<<dim3(18, 197), 256, 0, stream>>>(xb, wqkvb, Mr, Dm, qh, kh, vT, vcls, nullptr, nullptr);

  // merged cls + chunk attention (512 threads)
  attn_k<<<BH + BH * Ff, 512, 0, stream>>>(qh, kh, vT, vcls, xmask, ao);

  // output projection + bias: [25104,768] @ [768,768]^T -> f32 d_out
  gemm_k<1><<<dim3(6, 197), 256, 0, stream>>>(ao, wprojb, Mr, Dm, nullptr, nullptr, nullptr, nullptr, bproj, outp);
}